// Round 3
// baseline (912.822 us; speedup 1.0000x reference)
//
#include <hip/hip_runtime.h>
#include <hip/hip_bf16.h>

typedef __attribute__((ext_vector_type(8))) short short8;
typedef __attribute__((ext_vector_type(4))) float floatx4;

#define MFMA16(a, b, c) __builtin_amdgcn_mfma_f32_16x16x32_bf16((a), (b), (c), 0, 0, 0)

static constexpr int Bn = 2, Hn = 16, Sn = 2048, Dn = 64;
static constexpr int QT = 64;          // query rows per workgroup (4 waves x 16)
static constexpr int KT = 32;          // key cols per iteration
static constexpr int NIT = Sn / KT;    // 64 iterations
// LDS leading dims (bf16 elements); rows stay 16B-aligned, <=2-way bank aliasing (free)
static constexpr int KS_LD = 72;       // 64 + 8 pad  -> 144 B rows
static constexpr int VT_LD = 40;       // 32 + 8 pad  ->  80 B rows
static constexpr int PS_LD = 40;

__device__ __forceinline__ ushort f2bf(float f) {
    union { float f; unsigned int u; } c; c.f = f;
    unsigned int u = c.u;
    u += 0x7FFFu + ((u >> 16) & 1u);   // round-to-nearest-even
    return (ushort)(u >> 16);
}

// load 8 consecutive f32, convert to 8 bf16 (fragment or staging chunk)
__device__ __forceinline__ short8 ld8_bf(const float* __restrict__ p) {
    float4 a = *(const float4*)p;
    float4 b = *(const float4*)(p + 4);
    short8 r;
    r[0] = (short)f2bf(a.x); r[1] = (short)f2bf(a.y);
    r[2] = (short)f2bf(a.z); r[3] = (short)f2bf(a.w);
    r[4] = (short)f2bf(b.x); r[5] = (short)f2bf(b.y);
    r[6] = (short)f2bf(b.z); r[7] = (short)f2bf(b.w);
    return r;
}

__global__ __launch_bounds__(256) void sdpa_kernel(
    const float* __restrict__ Q,
    const float* __restrict__ K,
    const float* __restrict__ V,
    const int*   __restrict__ M,
    float* __restrict__ O,       // [B,H,S,D] f32
    float* __restrict__ A)       // [B,H,S,S] f32
{
    const int qt = blockIdx.x, h = blockIdx.y, b = blockIdx.z;
    const int tid  = threadIdx.x;
    const int wave = tid >> 6;
    const int lane = tid & 63;
    const int l16  = lane & 15;
    const int quad = lane >> 4;

    const size_t head = (size_t)(b * Hn + h) * Sn * Dn;
    const float* Qh = Q + head;
    const float* Kh = K + head;
    const float* Vh = V + head;
    const int q0  = qt * QT;
    const int qg0 = q0 + wave * 16;            // wave's first query row in head
    const int* Mb = M + (size_t)b * Sn * Sn;
    float* Ahead = A + (size_t)(b * Hn + h) * Sn * Sn;
    float* Ohead = O + head;

    __shared__ short Ks[KT * KS_LD];           // K tile bf16, row-major [kk][d]
    __shared__ short VT[Dn * VT_LD];           // V tile bf16 transposed [d][kk]
    __shared__ short Ps[4][16 * PS_LD];        // per-wave P transpose buffer

    // ---- Q fragments (A-operand), converted f32->bf16, held in registers ----
    short8 qf[2];
    {
        const float* qp = Qh + (size_t)(qg0 + l16) * Dn;
        qf[0] = ld8_bf(qp + quad * 8);
        qf[1] = ld8_bf(qp + 32 + quad * 8);
    }

    const int srow = tid >> 3;                 // staging: row 0..31
    const int scol = (tid & 7) * 8;            // staging: col 0..56

    // ================= pass A: masked row max & exp-sum (online) =============
    float mrow[4] = {-1e30f, -1e30f, -1e30f, -1e30f};
    float lrow[4] = {0.f, 0.f, 0.f, 0.f};

    for (int it = 0; it < NIT; ++it) {
        const int kk0 = it * KT;
        short8 kv = ld8_bf(Kh + (size_t)kk0 * Dn + tid * 8);
        *(short8*)(&Ks[srow * KS_LD + scol]) = kv;
        __syncthreads();

        floatx4 z = {0.f, 0.f, 0.f, 0.f};
        floatx4 sc[2] = {z, z};
        #pragma unroll
        for (int t = 0; t < 2; ++t) {
            #pragma unroll
            for (int c = 0; c < 2; ++c) {
                short8 kf = *(const short8*)(&Ks[(t * 16 + l16) * KS_LD + c * 32 + quad * 8]);
                sc[t] = MFMA16(qf[c], kf, sc[t]);
            }
        }

        // mask + scale; C layout: row = quad*4+r, col = t*16+l16
        float e[2][4];
        #pragma unroll
        for (int t = 0; t < 2; ++t)
            #pragma unroll
            for (int r = 0; r < 4; ++r) {
                int mv = Mb[(size_t)(qg0 + quad * 4 + r) * Sn + kk0 + t * 16 + l16];
                float x = sc[t][r] * 0.125f;
                e[t][r] = mv ? x : -10000.0f;
            }

        #pragma unroll
        for (int r = 0; r < 4; ++r) {
            float tmax = fmaxf(e[0][r], e[1][r]);
            #pragma unroll
            for (int off = 1; off < 16; off <<= 1)
                tmax = fmaxf(tmax, __shfl_xor(tmax, off));
            float mnew = fmaxf(mrow[r], tmax);
            float s = __expf(e[0][r] - mnew) + __expf(e[1][r] - mnew);
            #pragma unroll
            for (int off = 1; off < 16; off <<= 1)
                s += __shfl_xor(s, off);
            lrow[r] = lrow[r] * __expf(mrow[r] - mnew) + s;
            mrow[r] = mnew;
        }
        __syncthreads();
    }

    float invl[4];
    #pragma unroll
    for (int r = 0; r < 4; ++r) invl[r] = 1.0f / lrow[r];

    // ================= pass B: P write-out + O = P·V =========================
    floatx4 z0 = {0.f, 0.f, 0.f, 0.f};
    floatx4 oacc[4] = {z0, z0, z0, z0};

    for (int it = 0; it < NIT; ++it) {
        const int kk0 = it * KT;
        short8 kv = ld8_bf(Kh + (size_t)kk0 * Dn + tid * 8);
        short8 vv = ld8_bf(Vh + (size_t)kk0 * Dn + tid * 8);
        *(short8*)(&Ks[srow * KS_LD + scol]) = kv;
        #pragma unroll
        for (int j = 0; j < 8; ++j)               // transpose V into VT[d][kk]
            VT[(scol + j) * VT_LD + srow] = vv[j];
        __syncthreads();

        floatx4 z = {0.f, 0.f, 0.f, 0.f};
        floatx4 sc[2] = {z, z};
        #pragma unroll
        for (int t = 0; t < 2; ++t) {
            #pragma unroll
            for (int c = 0; c < 2; ++c) {
                short8 kf = *(const short8*)(&Ks[(t * 16 + l16) * KS_LD + c * 32 + quad * 8]);
                sc[t] = MFMA16(qf[c], kf, sc[t]);
            }
        }

        #pragma unroll
        for (int t = 0; t < 2; ++t)
            #pragma unroll
            for (int r = 0; r < 4; ++r) {
                int row = qg0 + quad * 4 + r;
                int col = kk0 + t * 16 + l16;
                int mv = Mb[(size_t)row * Sn + col];
                float x = sc[t][r] * 0.125f;
                x = mv ? x : -10000.0f;
                float p = __expf(x - mrow[r]) * invl[r];
                Ahead[(size_t)row * Sn + col] = p;                  // attention out (f32)
                Ps[wave][(quad * 4 + r) * PS_LD + t * 16 + l16] = (short)f2bf(p);
            }
        __syncthreads();

        // P (A-operand) and V^T (B-operand) fragments, then PV MFMAs
        short8 pf = *(const short8*)(&Ps[wave][l16 * PS_LD + quad * 8]);
        #pragma unroll
        for (int tn = 0; tn < 4; ++tn) {
            short8 vf = *(const short8*)(&VT[(tn * 16 + l16) * VT_LD + quad * 8]);
            oacc[tn] = MFMA16(pf, vf, oacc[tn]);
        }
        __syncthreads();
    }

    // epilogue: C layout row = quad*4+r, col(d) = tn*16+l16
    #pragma unroll
    for (int tn = 0; tn < 4; ++tn)
        #pragma unroll
        for (int r = 0; r < 4; ++r)
            Ohead[(size_t)(qg0 + quad * 4 + r) * Dn + tn * 16 + l16] = oacc[tn][r];
}

extern "C" void kernel_launch(void* const* d_in, const int* in_sizes, int n_in,
                              void* d_out, int out_size, void* d_ws, size_t ws_size,
                              hipStream_t stream) {
    const float* Q = (const float*)d_in[0];
    const float* K = (const float*)d_in[1];
    const float* V = (const float*)d_in[2];
    const int*   M = (const int*)d_in[3];
    float* O = (float*)d_out;
    float* A = O + (size_t)Bn * Hn * Sn * Dn;    // attention follows out
    dim3 grid(Sn / QT, Hn, Bn);                  // (32, 16, 2)
    sdpa_kernel<<<grid, 256, 0, stream>>>(Q, K, V, M, O, A);
}